// Round 6
// baseline (44.537 us; speedup 1.0000x reference)
//
#include <hip/hip_runtime.h>
#include <hip/hip_bf16.h>

// LLoCaAttention, MI355X. Two-kernel structure:
//  1) rot_cast_kv: per-particle rotation (blockdiag(1,Q^T)) + f32->bf16 for K,V.
//  2) lloca_attn: bf16 MFMA flash attention; Q rotated/packed in-prologue.
// R6: grid 1024 (4 blocks/CU, 4 waves/SIMD), double-buffered LDS with
// async-STAGE split (global->reg issued before compute, reg->LDS after),
// fixed m=0 softmax (scores O(1)), l-sum via ones-MFMA, permuted V-LDS.

#define NB 4
#define NH 8
#define NS 2048
#define NC 32

typedef float f32x4 __attribute__((ext_vector_type(4)));
typedef short s16x8 __attribute__((ext_vector_type(8)));

// 1/(C * ln2): fold softmax 1/C scale and log2-domain conversion into Q.
#define QSCALE 0.04511260931463978f

__device__ __forceinline__ short f2bf(float f) {  // RTNE f32 -> bf16 bits
  union { float f; unsigned u; } c; c.f = f;
  return (short)((c.u + 0x7FFFu + ((c.u >> 16) & 1u)) >> 16);
}

__device__ __forceinline__ void load_Q3(const float* __restrict__ F, int b, int n,
                                        float q9[9]) {
  const float* p = F + ((size_t)(b * NS + n)) * 16 + 5;  // rows/cols 1..3 of 4x4
  q9[0] = p[0]; q9[1] = p[1]; q9[2] = p[2];
  q9[3] = p[4]; q9[4] = p[5]; q9[5] = p[6];
  q9[6] = p[8]; q9[7] = p[9]; q9[8] = p[10];
}

// spatial part (elements 1..3) <- Q^T * spatial   [input transform]
__device__ __forceinline__ void rotT(const float q9[9], f32x4& v) {
  const float x = v[1], y = v[2], z = v[3];
  v[1] = q9[0] * x + q9[3] * y + q9[6] * z;
  v[2] = q9[1] * x + q9[4] * y + q9[7] * z;
  v[3] = q9[2] * x + q9[5] * y + q9[8] * z;
}

// spatial part <- Q * spatial     [output transform]
__device__ __forceinline__ void rotF(const float q9[9], f32x4& v) {
  const float x = v[1], y = v[2], z = v[3];
  v[1] = q9[0] * x + q9[1] * y + q9[2] * z;
  v[2] = q9[3] * x + q9[4] * y + q9[5] * z;
  v[3] = q9[6] * x + q9[7] * y + q9[8] * z;
}

// ---- pass 1: rotate + cast K,V to bf16 ----
__launch_bounds__(256)
__global__ void rot_cast_kv(const float* __restrict__ Kg,
                            const float* __restrict__ Vg,
                            const float* __restrict__ Fg,
                            unsigned short* __restrict__ Kbf,
                            unsigned short* __restrict__ Vbf) {
  const int gid  = blockIdx.x * 256 + threadIdx.x;   // 2 * 65536 rows
  const int tsel = gid >> 16;
  const int r    = gid & 65535;                      // (b*H + h)*N + n
  const int n    = r & (NS - 1);
  const int b    = r >> 14;
  const float* src = tsel == 0 ? Kg : Vg;
  unsigned short* dst = tsel == 0 ? Kbf : Vbf;
  const float* p = src + (size_t)r * NC;
  f32x4 c[8];
#pragma unroll
  for (int i = 0; i < 8; i++) c[i] = *(const f32x4*)(p + 4 * i);
  float q9[9]; load_Q3(Fg, b, n, q9);
#pragma unroll
  for (int i = 4; i < 8; i++) rotT(q9, c[i]);   // four-vectors (ch 16..31)
  unsigned short* o = dst + (size_t)r * NC;
#pragma unroll
  for (int i = 0; i < 8; i += 2) {
    s16x8 w;
#pragma unroll
    for (int e = 0; e < 4; e++) {
      w[e]     = f2bf(c[i][e]);
      w[4 + e] = f2bf(c[i + 1][e]);
    }
    *(s16x8*)(o + 4 * i) = w;
  }
}

// ---- pass 2: flash attention over pre-rotated bf16 K,V ----
__launch_bounds__(256, 4)
__global__ void lloca_attn(const float* __restrict__ Qg,
                           const unsigned short* __restrict__ Kbf,
                           const unsigned short* __restrict__ Vbf,
                           const float* __restrict__ Fg,
                           float* __restrict__ Og) {
  // Double-buffered. K tile: [128 keys][40 ch]. V^T tile: [32 ch][136 keys],
  // key order permuted within each 32-group so a lane's PV A-fragment is a
  // contiguous s16x8: within-group pos(c) = ((c>>2)&3)*8 + ((c>>4)&1)*4 + (c&3).
  __shared__ __align__(16) unsigned short Klds[2][128 * 40];
  __shared__ __align__(16) unsigned short Vlds[2][32 * 136];

  const int tid  = threadIdx.x;
  const int lane = tid & 63;
  const int wv   = tid >> 6;
  const int g    = lane >> 4;   // lane group 0..3
  const int lq   = lane & 15;   // query-within-tile (MFMA col)

  const int blk = blockIdx.x;   // 1024 = B(2b) H(3b) qb(5b)
  const int b   = blk >> 8;
  const int h   = (blk >> 5) & 7;
  const int qb  = blk & 31;

  const size_t bhr = (size_t)(b * NH + h) * NS;
  const unsigned short* Kp = Kbf + bhr * NC;
  const unsigned short* Vp = Vbf + bhr * NC;
  float*                Op = Og  + bhr * NC;

  const int qi = qb * 64 + wv * 16 + lq;  // this wave's q-tile (16 queries)

  const f32x4 zero4 = {0.f, 0.f, 0.f, 0.f};
  const short ONE = (short)0x3F80;  // bf16 1.0
  const s16x8 ones8 = {ONE, ONE, ONE, ONE, ONE, ONE, ONE, ONE};

  // ---- prologue: load + rotate + scale + pack own Q fragment ----
  s16x8 qfrag;
  {
    const float* qp = Qg + (bhr + qi) * NC + g * 8;  // slot (g,j) <-> ch 8g+j
    f32x4 a = *(const f32x4*)qp;
    f32x4 c = *(const f32x4*)(qp + 4);
    if (g >= 2) {  // g==2: vectors 0,1 ; g==3: vectors 2,3
      float q9[9]; load_Q3(Fg, b, qi, q9);
      rotT(q9, a);
      rotT(q9, c);
    }
#pragma unroll
    for (int e = 0; e < 4; e++) {
      qfrag[e]     = f2bf(a[e] * QSCALE);
      qfrag[4 + e] = f2bf(c[e] * QSCALE);
    }
  }

  f32x4 acc0 = zero4, acc1 = zero4, accL = zero4;

  // staging geometry (loop-invariant)
  const int key = tid >> 1, h2 = tid & 1;          // K: 128 keys x 2 halves
  const int kp2 = tid & 63, cb = tid >> 6;         // V: 64 key-pairs x 4 ch-blocks
  const int sub4   = (kp2 & 15) >> 1;
  const int newsub = (sub4 & 3) * 2 + (sub4 >> 2);
  const int vpos   = (kp2 >> 4) * 32 + newsub * 4 + 2 * (kp2 & 1);
  const unsigned short* kbase = Kp + (size_t)key * NC + h2 * 16;
  const unsigned short* vbase = Vp + (size_t)(2 * kp2) * NC + cb * 8;

  s16x8 rk0, rk1, rv0, rv1;  // in-flight tile registers

  // prologue stage tile 0
  rk0 = *(const s16x8*)kbase;
  rk1 = *(const s16x8*)(kbase + 8);
  rv0 = *(const s16x8*)vbase;
  rv1 = *(const s16x8*)(vbase + NC);

#define WRITE_TILE(buf)                                                        \
  do {                                                                         \
    *(s16x8*)&Klds[buf][key * 40 + h2 * 16]     = rk0;                         \
    *(s16x8*)&Klds[buf][key * 40 + h2 * 16 + 8] = rk1;                         \
    _Pragma("unroll")                                                          \
    for (int ch = 0; ch < 8; ch++) {                                           \
      unsigned uu = (unsigned)(unsigned short)rv0[ch] |                        \
                    ((unsigned)(unsigned short)rv1[ch] << 16);                 \
      *(unsigned*)&Vlds[buf][(cb * 8 + ch) * 136 + vpos] = uu;                 \
    }                                                                          \
  } while (0)

  WRITE_TILE(0);
  __syncthreads();

  const int NT = NS / 128;  // 16 tiles
  for (int i = 0; i < NT; i++) {
    const int cur = i & 1;
    if (i + 1 < NT) {  // issue next tile's global loads (latency hides under compute)
      const size_t off = (size_t)(i + 1) * 128 * NC;
      rk0 = *(const s16x8*)(kbase + off);
      rk1 = *(const s16x8*)(kbase + off + 8);
      rv0 = *(const s16x8*)(vbase + off);
      rv1 = *(const s16x8*)(vbase + off + NC);
    }
    // ---- compute on buf[cur]: 4 key-groups of 32 keys ----
#pragma unroll
    for (int kgi = 0; kgi < 4; kgi++) {
      const int kgb = kgi * 32;
      const s16x8 kf0 = *(const s16x8*)&Klds[cur][(kgb + lq) * 40 + g * 8];
      const s16x8 kf1 = *(const s16x8*)&Klds[cur][(kgb + 16 + lq) * 40 + g * 8];
      const s16x8 va0 = *(const s16x8*)&Vlds[cur][lq * 136 + kgb + g * 8];
      const s16x8 va1 = *(const s16x8*)&Vlds[cur][(16 + lq) * 136 + kgb + g * 8];
      // S^T = K_chunk * Q : lane holds scores for q=lq, keys kgb+4g+r / kgb+16+4g+r
      f32x4 s0 = __builtin_amdgcn_mfma_f32_16x16x32_bf16(kf0, qfrag, zero4, 0, 0, 0);
      f32x4 s1 = __builtin_amdgcn_mfma_f32_16x16x32_bf16(kf1, qfrag, zero4, 0, 0, 0);
      // m = 0 fixed: scores are q.k/C in log2 units; f32 exp2 overflow-safe.
      float p0 = __builtin_amdgcn_exp2f(s0[0]);
      float p1 = __builtin_amdgcn_exp2f(s0[1]);
      float p2 = __builtin_amdgcn_exp2f(s0[2]);
      float p3 = __builtin_amdgcn_exp2f(s0[3]);
      float p4 = __builtin_amdgcn_exp2f(s1[0]);
      float p5 = __builtin_amdgcn_exp2f(s1[1]);
      float p6 = __builtin_amdgcn_exp2f(s1[2]);
      float p7 = __builtin_amdgcn_exp2f(s1[3]);
      union { __hip_bfloat162 h2[4]; s16x8 v; } pk;
      pk.h2[0] = __float22bfloat162_rn(make_float2(p0, p1));
      pk.h2[1] = __float22bfloat162_rn(make_float2(p2, p3));
      pk.h2[2] = __float22bfloat162_rn(make_float2(p4, p5));
      pk.h2[3] = __float22bfloat162_rn(make_float2(p6, p7));
      // l-sum on the matrix pipe: every C row of (ones * P) = sum_k P[k][lq]
      accL = __builtin_amdgcn_mfma_f32_16x16x32_bf16(ones8, pk.v, accL, 0, 0, 0);
      acc0 = __builtin_amdgcn_mfma_f32_16x16x32_bf16(va0,   pk.v, acc0, 0, 0, 0);
      acc1 = __builtin_amdgcn_mfma_f32_16x16x32_bf16(va1,   pk.v, acc1, 0, 0, 0);
    }
    __syncthreads();  // all waves done reading buf[cur^1]'s successor target
    if (i + 1 < NT) {
      WRITE_TILE(cur ^ 1);
      __syncthreads();
    }
  }

  // ---- epilogue: normalize, rotate output vector g by Q_query, store.
  // O^T: col=q=lq, rows: ch 4g+r (acc0, scalars) / 16+4g+r (acc1, four-vector g)
  {
    const float inv = 1.0f / accL[0];
    float* op = Op + (size_t)qi * NC;
    f32x4 o0, o1;
#pragma unroll
    for (int r = 0; r < 4; r++) {
      o0[r] = acc0[r] * inv;
      o1[r] = acc1[r] * inv;
    }
    float q9[9]; load_Q3(Fg, b, qi, q9);
    rotF(q9, o1);
    *(f32x4*)(op + g * 4)      = o0;
    *(f32x4*)(op + 16 + g * 4) = o1;
  }
}

extern "C" void kernel_launch(void* const* d_in, const int* in_sizes, int n_in,
                              void* d_out, int out_size, void* d_ws, size_t ws_size,
                              hipStream_t stream) {
  (void)in_sizes; (void)n_in; (void)ws_size; (void)out_size;
  const float* q = (const float*)d_in[0];
  const float* k = (const float*)d_in[1];
  const float* v = (const float*)d_in[2];
  const float* f = (const float*)d_in[3];
  float* o = (float*)d_out;

  const size_t NEL = (size_t)NB * NH * NS * NC;  // 2,097,152 elements
  unsigned short* kbf = (unsigned short*)d_ws;
  unsigned short* vbf = kbf + NEL;

  hipLaunchKernelGGL(rot_cast_kv, dim3(512), dim3(256), 0, stream,
                     k, v, f, kbf, vbf);
  hipLaunchKernelGGL(lloca_attn, dim3(1024), dim3(256), 0, stream,
                     q, kbf, vbf, f, o);
}